// Round 1
// baseline (167.646 us; speedup 1.0000x reference)
//
#include <hip/hip_runtime.h>
#include <cstdint>
#include <cstddef>

typedef __bf16 bf16x8 __attribute__((ext_vector_type(8)));
typedef float f32x4 __attribute__((ext_vector_type(4)));

#define B_ 8
#define T_ 2048
#define C_ 1024
#define H_ 128

__device__ __forceinline__ unsigned short f2bf(float f) {
    union { float f; unsigned int u; } x; x.f = f;
    unsigned int r = x.u + 0x7fffu + ((x.u >> 16) & 1u);
    return (unsigned short)(r >> 16);
}

// ---------------------------------------------------------------------------
// Projection: out[m][n] = x[m][:] @ W[:][n] + bias[n], computed in bf16 MFMA,
// f32 inputs converted on the fly. blockIdx.y selects q/k/v. v is stored
// TRANSPOSED (vT[b][d][t]) so attention's PV B-operand reads are k-contiguous.
// ---------------------------------------------------------------------------
__global__ __launch_bounds__(256) void proj_kernel(
    const float* __restrict__ x,
    const float* __restrict__ Wq, const float* __restrict__ bq,
    const float* __restrict__ Wk, const float* __restrict__ bk,
    const float* __restrict__ Wv, const float* __restrict__ bv,
    unsigned short* __restrict__ qo, unsigned short* __restrict__ ko,
    unsigned short* __restrict__ vo)
{
    const int which = blockIdx.y;
    const float* W    = which == 0 ? Wq : (which == 1 ? Wk : Wv);
    const float* bias = which == 0 ? bq : (which == 1 ? bk : bv);

    __shared__ unsigned short xs[128 * 64];   // [m][kk] bf16, XOR-swizzled
    __shared__ unsigned short wt[128 * 64];   // W^T: [n][kk] bf16, XOR-swizzled

    const int tid = threadIdx.x;
    const int w = tid >> 6, l = tid & 63, g = l >> 4, lc = l & 15;
    const int wm = w & 1, wn = w >> 1;
    const int m0 = blockIdx.x * 128;

    f32x4 acc[4][4];
    #pragma unroll
    for (int i = 0; i < 4; ++i)
        #pragma unroll
        for (int j = 0; j < 4; ++j) acc[i][j] = f32x4{0.f, 0.f, 0.f, 0.f};

    for (int kc = 0; kc < 16; ++kc) {
        const int kb = kc * 64;
        // stage x tile [128][64] f32 -> bf16 LDS (swizzled rows)
        #pragma unroll
        for (int j = 0; j < 8; ++j) {
            int e = (j * 256 + tid) * 4;
            int m = e >> 6, kk = e & 63;
            const float4 v4 = *(const float4*)&x[(size_t)(m0 + m) * C_ + kb + kk];
            int idx = (m * 64 + kk) ^ ((m & 7) << 3);
            unsigned int u0 = (unsigned int)f2bf(v4.x) | ((unsigned int)f2bf(v4.y) << 16);
            unsigned int u1 = (unsigned int)f2bf(v4.z) | ((unsigned int)f2bf(v4.w) << 16);
            *(uint2*)&xs[idx] = make_uint2(u0, u1);
        }
        // stage W^T tile: global W[kk][n] row-major -> wt[n][kk] (scalar transpose writes)
        #pragma unroll
        for (int j = 0; j < 8; ++j) {
            int e = (j * 256 + tid) * 4;
            int kk = e >> 7, n = e & 127;
            const float4 v4 = *(const float4*)&W[(size_t)(kb + kk) * H_ + n];
            wt[((n + 0) * 64 + kk) ^ (((n + 0) & 7) << 3)] = f2bf(v4.x);
            wt[((n + 1) * 64 + kk) ^ (((n + 1) & 7) << 3)] = f2bf(v4.y);
            wt[((n + 2) * 64 + kk) ^ (((n + 2) & 7) << 3)] = f2bf(v4.z);
            wt[((n + 3) * 64 + kk) ^ (((n + 3) & 7) << 3)] = f2bf(v4.w);
        }
        __syncthreads();
        #pragma unroll
        for (int ks = 0; ks < 2; ++ks) {
            const int kko = ks * 32 + g * 8;
            bf16x8 a[4], bfr[4];
            #pragma unroll
            for (int im = 0; im < 4; ++im) {
                int row = wm * 64 + im * 16 + lc;
                a[im] = *(const bf16x8*)&xs[(row * 64 + kko) ^ ((row & 7) << 3)];
            }
            #pragma unroll
            for (int jn = 0; jn < 4; ++jn) {
                int n = wn * 64 + jn * 16 + lc;
                bfr[jn] = *(const bf16x8*)&wt[(n * 64 + kko) ^ ((n & 7) << 3)];
            }
            #pragma unroll
            for (int im = 0; im < 4; ++im)
                #pragma unroll
                for (int jn = 0; jn < 4; ++jn)
                    acc[im][jn] = __builtin_amdgcn_mfma_f32_16x16x32_bf16(
                        a[im], bfr[jn], acc[im][jn], 0, 0, 0);
        }
        __syncthreads();
    }
    // epilogue: C/D layout col = lane&15, row = (lane>>4)*4 + reg
    #pragma unroll
    for (int jn = 0; jn < 4; ++jn) {
        int n = wn * 64 + jn * 16 + lc;
        float bval = bias[n];
        #pragma unroll
        for (int im = 0; im < 4; ++im) {
            #pragma unroll
            for (int r = 0; r < 4; ++r) {
                int m = m0 + wm * 64 + im * 16 + g * 4 + r;
                unsigned short val = f2bf(acc[im][jn][r] + bval);
                if (which == 2) {
                    int bi = m >> 11, t = m & (T_ - 1);
                    vo[((size_t)bi * H_ + n) * T_ + t] = val;   // transposed store
                } else {
                    unsigned short* o = which == 0 ? qo : ko;
                    o[(size_t)m * H_ + n] = val;
                }
            }
        }
    }
}

// ---------------------------------------------------------------------------
// Causal flash attention. 64-row Q tile per block, 4 waves x 16 rows.
// Q in registers; K [64][128] and V^T [128][64] staged in swizzled LDS;
// online softmax with 16-lane butterfly; P through per-wave swizzled LDS.
// ---------------------------------------------------------------------------
__global__ __launch_bounds__(256) void attn_kernel(
    const unsigned short* __restrict__ q,
    const unsigned short* __restrict__ k,
    const unsigned short* __restrict__ vT,
    float* __restrict__ out)
{
    const int qt = blockIdx.x, bb = blockIdx.y;
    const int q0 = qt * 64;
    const unsigned short* qb = q  + (size_t)bb * T_ * H_;
    const unsigned short* kb = k  + (size_t)bb * T_ * H_;
    const unsigned short* vb = vT + (size_t)bb * H_ * T_;

    __shared__ unsigned short Ks[64 * 128];    // [key][d]  swizzled
    __shared__ unsigned short Vs[128 * 64];    // [d][key]  swizzled
    __shared__ unsigned short Ps[4][16 * 64];  // per-wave P [qr][key] swizzled

    const int tid = threadIdx.x;
    const int w = tid >> 6, l = tid & 63, g = l >> 4, lc = l & 15;

    // Q fragments for this wave's 16 rows, kept for the whole kernel
    bf16x8 aq[4];
    #pragma unroll
    for (int ds = 0; ds < 4; ++ds)
        aq[ds] = *(const bf16x8*)&qb[(size_t)(q0 + w * 16 + lc) * H_ + ds * 32 + g * 8];

    f32x4 o[8];
    #pragma unroll
    for (int jo = 0; jo < 8; ++jo) o[jo] = f32x4{0.f, 0.f, 0.f, 0.f};
    float m_run[4], l_run[4];
    #pragma unroll
    for (int r = 0; r < 4; ++r) { m_run[r] = -INFINITY; l_run[r] = 0.f; }

    const int nt = qt + 1;
    for (int t = 0; t < nt; ++t) {
        const int kv0 = t * 64;
        #pragma unroll
        for (int j = 0; j < 4; ++j) {       // stage K tile
            int e = (j * 256 + tid) * 8;
            int key = e >> 7, d = e & 127;
            uint4 val = *(const uint4*)&kb[(size_t)(kv0 + key) * H_ + d];
            *(uint4*)&Ks[(key * 128 + d) ^ ((key & 7) << 3)] = val;
        }
        #pragma unroll
        for (int j = 0; j < 4; ++j) {       // stage V^T tile
            int e = (j * 256 + tid) * 8;
            int d = e >> 6, kl = e & 63;
            uint4 val = *(const uint4*)&vb[(size_t)d * T_ + kv0 + kl];
            *(uint4*)&Vs[(d * 64 + kl) ^ ((d & 7) << 3)] = val;
        }
        __syncthreads();

        // S = Q K^T  (rows = q, cols = key)
        f32x4 s[4];
        #pragma unroll
        for (int jk = 0; jk < 4; ++jk) s[jk] = f32x4{0.f, 0.f, 0.f, 0.f};
        #pragma unroll
        for (int ds = 0; ds < 4; ++ds) {
            #pragma unroll
            for (int jk = 0; jk < 4; ++jk) {
                int row = jk * 16 + lc;
                bf16x8 bf = *(const bf16x8*)&Ks[(row * 128 + ds * 32 + g * 8) ^ ((row & 7) << 3)];
                s[jk] = __builtin_amdgcn_mfma_f32_16x16x32_bf16(aq[ds], bf, s[jk], 0, 0, 0);
            }
        }
        // scale + causal mask (only the diagonal tile is partial)
        const bool diag = (t == qt);
        #pragma unroll
        for (int jk = 0; jk < 4; ++jk)
            #pragma unroll
            for (int r = 0; r < 4; ++r) {
                float v = s[jk][r] * 0.03125f;   // C^-0.5 = 1/32
                if (diag && (jk * 16 + lc > w * 16 + g * 4 + r)) v = -1e30f;
                s[jk][r] = v;
            }
        // online softmax: keys live on lane&15 (x4 frags); butterfly over 16 lanes
        float pm[4];
        #pragma unroll
        for (int r = 0; r < 4; ++r)
            pm[r] = fmaxf(fmaxf(s[0][r], s[1][r]), fmaxf(s[2][r], s[3][r]));
        #pragma unroll
        for (int off = 1; off < 16; off <<= 1)
            #pragma unroll
            for (int r = 0; r < 4; ++r)
                pm[r] = fmaxf(pm[r], __shfl_xor(pm[r], off, 64));
        float scl[4], rs[4];
        #pragma unroll
        for (int r = 0; r < 4; ++r) {
            float mn = fmaxf(m_run[r], pm[r]);
            scl[r] = __expf(m_run[r] - mn);
            m_run[r] = mn;
            rs[r] = 0.f;
        }
        #pragma unroll
        for (int jk = 0; jk < 4; ++jk)
            #pragma unroll
            for (int r = 0; r < 4; ++r) {
                float p = __expf(s[jk][r] - m_run[r]);
                s[jk][r] = p;
                rs[r] += p;
            }
        #pragma unroll
        for (int off = 1; off < 16; off <<= 1)
            #pragma unroll
            for (int r = 0; r < 4; ++r)
                rs[r] += __shfl_xor(rs[r], off, 64);
        #pragma unroll
        for (int r = 0; r < 4; ++r)
            l_run[r] = l_run[r] * scl[r] + rs[r];
        #pragma unroll
        for (int jo = 0; jo < 8; ++jo)
            #pragma unroll
            for (int r = 0; r < 4; ++r)
                o[jo][r] *= scl[r];
        // P -> per-wave LDS (re-layout for PV A-operand)
        #pragma unroll
        for (int jk = 0; jk < 4; ++jk)
            #pragma unroll
            for (int r = 0; r < 4; ++r) {
                int row = g * 4 + r;
                Ps[w][(row * 64 + jk * 16 + lc) ^ ((row & 7) << 3)] = f2bf(s[jk][r]);
            }
        // O += P @ V
        #pragma unroll
        for (int ks = 0; ks < 2; ++ks) {
            bf16x8 pa = *(const bf16x8*)&Ps[w][(lc * 64 + ks * 32 + g * 8) ^ ((lc & 7) << 3)];
            #pragma unroll
            for (int jo = 0; jo < 8; ++jo) {
                int row = jo * 16 + lc;
                bf16x8 bv_ = *(const bf16x8*)&Vs[(row * 64 + ks * 32 + g * 8) ^ ((row & 7) << 3)];
                o[jo] = __builtin_amdgcn_mfma_f32_16x16x32_bf16(pa, bv_, o[jo], 0, 0, 0);
            }
        }
        __syncthreads();
    }
    // epilogue: out = o / l
    float* ob = out + (size_t)bb * T_ * H_;
    #pragma unroll
    for (int jo = 0; jo < 8; ++jo)
        #pragma unroll
        for (int r = 0; r < 4; ++r)
            ob[(size_t)(q0 + w * 16 + g * 4 + r) * H_ + jo * 16 + lc] = o[jo][r] / l_run[r];
}

extern "C" void kernel_launch(void* const* d_in, const int* in_sizes, int n_in,
                              void* d_out, int out_size, void* d_ws, size_t ws_size,
                              hipStream_t stream) {
    const float* x  = (const float*)d_in[0];
    const float* Wq = (const float*)d_in[1];
    const float* bq = (const float*)d_in[2];
    const float* Wk = (const float*)d_in[3];
    const float* bk = (const float*)d_in[4];
    const float* Wv = (const float*)d_in[5];
    const float* bv = (const float*)d_in[6];
    float* out = (float*)d_out;

    unsigned short* qws = (unsigned short*)d_ws;           // [B,T,H] bf16, 4 MB
    unsigned short* kws = qws + (size_t)B_ * T_ * H_;      // [B,T,H] bf16, 4 MB
    unsigned short* vws = kws + (size_t)B_ * T_ * H_;      // [B,H,T] bf16 (transposed), 4 MB

    proj_kernel<<<dim3(128, 3), 256, 0, stream>>>(x, Wq, bq, Wk, bk, Wv, bv, qws, kws, vws);
    attn_kernel<<<dim3(32, 8), 256, 0, stream>>>(qws, kws, vws, out);
}

// Round 2
// 103.446 us; speedup vs baseline: 1.6206x; 1.6206x over previous
//
#include <hip/hip_runtime.h>
#include <cstdint>
#include <cstddef>

typedef __bf16 bf16x8 __attribute__((ext_vector_type(8)));
typedef float f32x4 __attribute__((ext_vector_type(4)));

#define B_ 8
#define T_ 2048
#define C_ 1024
#define H_ 128

__device__ __forceinline__ unsigned short f2bf(float f) {
    __bf16 h = (__bf16)f;
    return *(unsigned short*)&h;
}

// async global->LDS, 16B per lane. LDS dest must be the wave-uniform base;
// HW adds lane*16. Global src is per-lane.
__device__ __forceinline__ void gload16(void* lds, const void* g) {
    __builtin_amdgcn_global_load_lds(
        (const __attribute__((address_space(1))) unsigned int*)g,
        (__attribute__((address_space(3))) unsigned int*)lds, 16, 0, 0);
}

// ---------------------------------------------------------------------------
// prep_w: WT[which][n][k] bf16  <-  W[k][n] f32.  Tiny (1.5 MB read).
// ---------------------------------------------------------------------------
__global__ __launch_bounds__(256) void prep_w(
    const float* __restrict__ Wq, const float* __restrict__ Wk,
    const float* __restrict__ Wv, unsigned short* __restrict__ wt)
{
    int gid = blockIdx.x * 256 + threadIdx.x;        // 49152 total
    int which = gid >> 14;
    int rem = gid & 16383;
    int n = rem >> 7;            // 0..127
    int kc = rem & 127;          // k-chunk of 8
    const float* W = which == 0 ? Wq : (which == 1 ? Wk : Wv);
    unsigned short tmp[8];
    #pragma unroll
    for (int i = 0; i < 8; ++i) tmp[i] = f2bf(W[(size_t)(kc * 8 + i) * H_ + n]);
    *(uint4*)&wt[((size_t)which * H_ + n) * C_ + kc * 8] = *(uint4*)tmp;
}

// ---------------------------------------------------------------------------
// proj: out = x @ W + b in bf16 MFMA. BM=64, BN=128, BK=64, 4 waves (2Mx2N),
// double-buffered: W^T via global_load_lds (pre-swizzled source), x f32 loaded
// early / converted+stored late (async split). which==2 stores V transposed.
// ---------------------------------------------------------------------------
__global__ __launch_bounds__(256) void proj_kernel(
    const float* __restrict__ x, const unsigned short* __restrict__ wt,
    const float* __restrict__ bq, const float* __restrict__ bk,
    const float* __restrict__ bv,
    unsigned short* __restrict__ qo, unsigned short* __restrict__ ko,
    unsigned short* __restrict__ vo)
{
    const int which = blockIdx.y;
    const float* bias = which == 0 ? bq : (which == 1 ? bk : bv);

    __shared__ unsigned short xs[2][64 * 64];    // [m][k] bf16, chunk-XOR swizzled
    __shared__ unsigned short ws2[2][128 * 64];  // [n][k] bf16, chunk-XOR swizzled

    const int tid = threadIdx.x;
    const int w = tid >> 6, l = tid & 63, g = l >> 4, lc = l & 15;
    const int wm = w & 1, wn = w >> 1;
    const int m0 = blockIdx.x * 64;

    // x staging geometry: thread -> (row sr, chunk pair sc2)
    const int sr = tid >> 2;
    const int sc2 = (tid & 3) * 2;
    const float* xrow = &x[(size_t)(m0 + sr) * C_ + sc2 * 8];
    const int xst0 = (sr * 8 + (sc2 ^ (sr & 7))) * 8;
    const int xst1 = (sr * 8 + ((sc2 + 1) ^ (sr & 7))) * 8;

    const unsigned short* wbase = &wt[(size_t)which * H_ * C_];

    f32x4 acc[2][4];
    #pragma unroll
    for (int im = 0; im < 2; ++im)
        #pragma unroll
        for (int jn = 0; jn < 4; ++jn) acc[im][jn] = f32x4{0.f, 0.f, 0.f, 0.f};

    float xr[16];
    // ---- prologue: stage kc=0 into buf 0
    #pragma unroll
    for (int j = 0; j < 4; ++j) {
        int slot = w * 256 + j * 64 + l;
        int r = slot >> 3, cs = slot & 7;
        gload16(&ws2[0][(w * 256 + j * 64) * 8],
                &wbase[(size_t)r * C_ + ((cs ^ (r & 7)) * 8)]);
    }
    #pragma unroll
    for (int i = 0; i < 4; ++i) {
        float4 v4 = *(const float4*)(xrow + i * 4);
        xr[i * 4 + 0] = v4.x; xr[i * 4 + 1] = v4.y;
        xr[i * 4 + 2] = v4.z; xr[i * 4 + 3] = v4.w;
    }
    {
        unsigned short tb[16];
        #pragma unroll
        for (int i = 0; i < 16; ++i) tb[i] = f2bf(xr[i]);
        *(uint4*)&xs[0][xst0] = *(uint4*)&tb[0];
        *(uint4*)&xs[0][xst1] = *(uint4*)&tb[8];
    }
    __syncthreads();

    int cur = 0;
    for (int kc = 0; kc < 16; ++kc) {
        const int nxt = cur ^ 1;
        const int kb2 = (kc + 1) * 64;
        if (kc < 15) {
            #pragma unroll
            for (int j = 0; j < 4; ++j) {
                int slot = w * 256 + j * 64 + l;
                int r = slot >> 3, cs = slot & 7;
                gload16(&ws2[nxt][(w * 256 + j * 64) * 8],
                        &wbase[(size_t)r * C_ + kb2 + ((cs ^ (r & 7)) * 8)]);
            }
            #pragma unroll
            for (int i = 0; i < 4; ++i) {
                float4 v4 = *(const float4*)(xrow + kb2 + i * 4);
                xr[i * 4 + 0] = v4.x; xr[i * 4 + 1] = v4.y;
                xr[i * 4 + 2] = v4.z; xr[i * 4 + 3] = v4.w;
            }
        }
        // ---- compute on cur
        #pragma unroll
        for (int ks = 0; ks < 2; ++ks) {
            bf16x8 a[2], b[4];
            #pragma unroll
            for (int im = 0; im < 2; ++im) {
                int row = wm * 32 + im * 16 + lc;
                a[im] = *(const bf16x8*)&xs[cur][(row * 8 + ((ks * 4 + g) ^ (row & 7))) * 8];
            }
            #pragma unroll
            for (int jn = 0; jn < 4; ++jn) {
                int n = wn * 64 + jn * 16 + lc;
                b[jn] = *(const bf16x8*)&ws2[cur][(n * 8 + ((ks * 4 + g) ^ (n & 7))) * 8];
            }
            #pragma unroll
            for (int im = 0; im < 2; ++im)
                #pragma unroll
                for (int jn = 0; jn < 4; ++jn)
                    acc[im][jn] = __builtin_amdgcn_mfma_f32_16x16x32_bf16(
                        a[im], b[jn], acc[im][jn], 0, 0, 0);
        }
        if (kc < 15) {
            unsigned short tb[16];
            #pragma unroll
            for (int i = 0; i < 16; ++i) tb[i] = f2bf(xr[i]);
            *(uint4*)&xs[nxt][xst0] = *(uint4*)&tb[0];
            *(uint4*)&xs[nxt][xst1] = *(uint4*)&tb[8];
        }
        __syncthreads();
        cur = nxt;
    }

    // ---- epilogue: bias + repack through LDS for coalesced 16B stores
    unsigned short* eb = &xs[0][0];   // 8192 elems = 16 KB, exactly [64][128]
    if (which != 2) {
        #pragma unroll
        for (int jn = 0; jn < 4; ++jn) {
            int n = wn * 64 + jn * 16 + lc;
            float bval = bias[n];
            #pragma unroll
            for (int im = 0; im < 2; ++im)
                #pragma unroll
                for (int r = 0; r < 4; ++r) {
                    int ml = wm * 32 + im * 16 + g * 4 + r;
                    eb[ml * 128 + n] = f2bf(acc[im][jn][r] + bval);
                }
        }
        __syncthreads();
        unsigned short* o = which == 0 ? qo : ko;
        #pragma unroll
        for (int i = 0; i < 4; ++i) {
            int cidx = i * 256 + tid;          // 0..1023
            int row = cidx >> 4, c16 = cidx & 15;
            *(uint4*)&o[(size_t)(m0 + row) * H_ + c16 * 8] =
                *(const uint4*)&eb[row * 128 + c16 * 8];
        }
    } else {
        #pragma unroll
        for (int jn = 0; jn < 4; ++jn) {
            int n = wn * 64 + jn * 16 + lc;
            float bval = bias[n];
            #pragma unroll
            for (int im = 0; im < 2; ++im)
                #pragma unroll
                for (int r = 0; r < 4; ++r) {
                    int ml = wm * 32 + im * 16 + g * 4 + r;
                    eb[n * 64 + ml] = f2bf(acc[im][jn][r] + bval);
                }
        }
        __syncthreads();
        const int bi = m0 >> 11, t0 = m0 & (T_ - 1);
        #pragma unroll
        for (int i = 0; i < 4; ++i) {
            int cidx = i * 256 + tid;          // 0..1023
            int n = cidx >> 3, cc = cidx & 7;
            *(uint4*)&vo[((size_t)(bi * H_ + n)) * T_ + t0 + cc * 8] =
                *(const uint4*)&eb[n * 64 + cc * 8];
        }
    }
}

// ---------------------------------------------------------------------------
// Causal flash attention. QBLK=32 (2 waves x 16 rows), KVBLK=64, grid 64x8
// with longest-first remap. K/V double-buffered via global_load_lds with
// pre-swizzled source; Q in registers; P via per-wave swizzled LDS.
// ---------------------------------------------------------------------------
__global__ __launch_bounds__(128) void attn_kernel(
    const unsigned short* __restrict__ q,
    const unsigned short* __restrict__ k,
    const unsigned short* __restrict__ vT,
    float* __restrict__ out)
{
    const int qt = (gridDim.x - 1) - blockIdx.x;   // long blocks dispatched first
    const int bb = blockIdx.y;
    const int q0 = qt * 32;
    const unsigned short* qb = q  + (size_t)bb * T_ * H_;
    const unsigned short* kb = k  + (size_t)bb * T_ * H_;
    const unsigned short* vb = vT + (size_t)bb * H_ * T_;

    __shared__ unsigned short Ks[2][64 * 128];   // [key][d]  chunk-XOR swizzled
    __shared__ unsigned short Vs[2][128 * 64];   // [d][key]  chunk-XOR swizzled
    __shared__ unsigned short Ps[2][16 * 64];    // per-wave P, swizzled

    const int tid = threadIdx.x;
    const int w = tid >> 6, l = tid & 63, g = l >> 4, lc = l & 15;

    bf16x8 aq[4];
    #pragma unroll
    for (int ds = 0; ds < 4; ++ds)
        aq[ds] = *(const bf16x8*)&qb[(size_t)(q0 + w * 16 + lc) * H_ + ds * 32 + g * 8];

    f32x4 o[8];
    #pragma unroll
    for (int jo = 0; jo < 8; ++jo) o[jo] = f32x4{0.f, 0.f, 0.f, 0.f};
    float m_run[4], l_run[4];
    #pragma unroll
    for (int r = 0; r < 4; ++r) { m_run[r] = -INFINITY; l_run[r] = 0.f; }

    const int tl = q0 >> 6;
    const int nt = tl + 1;

    auto stageKV = [&](int buf, int t) {
        const int kv0 = t * 64;
        #pragma unroll
        for (int j = 0; j < 8; ++j) {
            int slot = w * 512 + j * 64 + l;
            int r = slot >> 4, cs = slot & 15;
            gload16(&Ks[buf][(w * 512 + j * 64) * 8],
                    &kb[(size_t)(kv0 + r) * H_ + ((cs ^ (r & 7)) * 8)]);
        }
        #pragma unroll
        for (int j = 0; j < 8; ++j) {
            int slot = w * 512 + j * 64 + l;
            int r = slot >> 3, cs = slot & 7;
            gload16(&Vs[buf][(w * 512 + j * 64) * 8],
                    &vb[(size_t)r * T_ + kv0 + ((cs ^ (r & 7)) * 8)]);
        }
    };

    stageKV(0, 0);
    __syncthreads();

    int cur = 0;
    for (int t = 0; t < nt; ++t) {
        if (t + 1 < nt) stageKV(cur ^ 1, t + 1);

        const int kv0 = t * 64;
        // S = Q K^T
        f32x4 s[4];
        #pragma unroll
        for (int jk = 0; jk < 4; ++jk) s[jk] = f32x4{0.f, 0.f, 0.f, 0.f};
        #pragma unroll
        for (int ds = 0; ds < 4; ++ds) {
            #pragma unroll
            for (int jk = 0; jk < 4; ++jk) {
                int row = jk * 16 + lc;
                bf16x8 bf = *(const bf16x8*)&Ks[cur][(row * 16 + ((ds * 4 + g) ^ (row & 7))) * 8];
                s[jk] = __builtin_amdgcn_mfma_f32_16x16x32_bf16(aq[ds], bf, s[jk], 0, 0, 0);
            }
        }
        // scale + causal mask (diag tile only)
        const bool diag = (t == tl);
        const int rowg = q0 + w * 16 + g * 4;
        #pragma unroll
        for (int jk = 0; jk < 4; ++jk)
            #pragma unroll
            for (int r = 0; r < 4; ++r) {
                float v = s[jk][r] * 0.03125f;           // C^-0.5
                if (diag && (kv0 + jk * 16 + lc > rowg + r)) v = -1e30f;
                s[jk][r] = v;
            }
        // online softmax (keys on lc x 4 frags; 16-lane butterfly)
        float pm[4];
        #pragma unroll
        for (int r = 0; r < 4; ++r)
            pm[r] = fmaxf(fmaxf(s[0][r], s[1][r]), fmaxf(s[2][r], s[3][r]));
        #pragma unroll
        for (int off = 1; off < 16; off <<= 1)
            #pragma unroll
            for (int r = 0; r < 4; ++r)
                pm[r] = fmaxf(pm[r], __shfl_xor(pm[r], off, 64));
        float scl[4], rs[4];
        #pragma unroll
        for (int r = 0; r < 4; ++r) {
            float mn = fmaxf(m_run[r], pm[r]);
            scl[r] = __expf(m_run[r] - mn);
            m_run[r] = mn;
            rs[r] = 0.f;
        }
        #pragma unroll
        for (int jk = 0; jk < 4; ++jk)
            #pragma unroll
            for (int r = 0; r < 4; ++r) {
                float p = __expf(s[jk][r] - m_run[r]);
                s[jk][r] = p;
                rs[r] += p;
            }
        #pragma unroll
        for (int off = 1; off < 16; off <<= 1)
            #pragma unroll
            for (int r = 0; r < 4; ++r)
                rs[r] += __shfl_xor(rs[r], off, 64);
        #pragma unroll
        for (int r = 0; r < 4; ++r)
            l_run[r] = l_run[r] * scl[r] + rs[r];
        #pragma unroll
        for (int jo = 0; jo < 8; ++jo)
            #pragma unroll
            for (int r = 0; r < 4; ++r)
                o[jo][r] *= scl[r];
        // P -> per-wave LDS
        #pragma unroll
        for (int jk = 0; jk < 4; ++jk)
            #pragma unroll
            for (int r = 0; r < 4; ++r) {
                int row = g * 4 + r;
                Ps[w][(row * 64 + jk * 16 + lc) ^ ((row & 7) << 3)] = f2bf(s[jk][r]);
            }
        // O += P @ V
        #pragma unroll
        for (int ks = 0; ks < 2; ++ks) {
            bf16x8 pa = *(const bf16x8*)&Ps[w][(lc * 64 + ks * 32 + g * 8) ^ ((lc & 7) << 3)];
            #pragma unroll
            for (int jo = 0; jo < 8; ++jo) {
                int row = jo * 16 + lc;
                bf16x8 bv_ = *(const bf16x8*)&Vs[cur][(row * 8 + ((ks * 4 + g) ^ (row & 7))) * 8];
                o[jo] = __builtin_amdgcn_mfma_f32_16x16x32_bf16(pa, bv_, o[jo], 0, 0, 0);
            }
        }
        __syncthreads();
        cur ^= 1;
    }

    float* ob = out + (size_t)bb * T_ * H_;
    #pragma unroll
    for (int jo = 0; jo < 8; ++jo)
        #pragma unroll
        for (int r = 0; r < 4; ++r)
            ob[(size_t)(q0 + w * 16 + g * 4 + r) * H_ + jo * 16 + lc] = o[jo][r] / l_run[r];
}

extern "C" void kernel_launch(void* const* d_in, const int* in_sizes, int n_in,
                              void* d_out, int out_size, void* d_ws, size_t ws_size,
                              hipStream_t stream) {
    const float* x  = (const float*)d_in[0];
    const float* Wq = (const float*)d_in[1];
    const float* bq = (const float*)d_in[2];
    const float* Wk = (const float*)d_in[3];
    const float* bk = (const float*)d_in[4];
    const float* Wv = (const float*)d_in[5];
    const float* bv = (const float*)d_in[6];
    float* out = (float*)d_out;

    unsigned short* qws = (unsigned short*)d_ws;            // [B,T,H] bf16
    unsigned short* kws = qws + (size_t)B_ * T_ * H_;       // [B,T,H] bf16
    unsigned short* vws = kws + (size_t)B_ * T_ * H_;       // [B,H,T] bf16 (transposed)
    unsigned short* wtw = vws + (size_t)B_ * H_ * T_;       // [3,H,C] bf16 (W^T)

    prep_w<<<dim3(192), 256, 0, stream>>>(Wq, Wk, Wv, wtw);
    proj_kernel<<<dim3(256, 3), 256, 0, stream>>>(x, wtw, bq, bk, bv, qws, kws, vws);
    attn_kernel<<<dim3(64, 8), 128, 0, stream>>>(qws, kws, vws, out);
}